// Round 4
// baseline (357.711 us; speedup 1.0000x reference)
//
#include <hip/hip_runtime.h>
#include <hip/hip_bf16.h>
#include <hip/hip_fp16.h>
#include <cstddef>

// ---------------------------------------------------------------------------
// GCN 2-layer forward.
//  h1 = relu(Agg(x @ W1) + b1);  out = log_softmax(Agg(h1 @ W2) + b2)
//  Agg(z)[i] = dinv[i]^2 z[i] + sum_{e: col[e]==i} dinv[row] w dinv[i] z[row]
// Round 6: feature-sliced aggregation (L2-resident gathers).
//  * Diagnosis: gather table (12.8MB) >> 4MB/XCD L2 with random sources ->
//    178MB of L2-miss line refetch at ~4TB/s was the agg1 wall.
//  * aggs_kernel: pass p gathers only bytes [64p,64p+64) of each row ->
//    3.2MB slice fits every XCD L2. agg1 = 4 passes, agg2 = 2 passes,
//    each pass writes its 32 output columns (bias/relu fused).
//  * log_softmax split into tiny elementwise lsm_kernel (agg2 passes write
//    raw logits).
//  * edge records packed to 4B (src:u16, w:fp16) -> halves record stream.
//  * GEMMs via bf16 MFMA (16x16x32), dinv-scaling fused epilogue (unchanged).
// ---------------------------------------------------------------------------

#define DIN 256
#define DH  128
#define DOUT 64
#define NPB 100        // nodes per bucket (50000/100 = 500 buckets)
#define NBMAX 512      // max buckets (shared-array size)

typedef __bf16 bf16x8 __attribute__((ext_vector_type(8)));
typedef float f32x4 __attribute__((ext_vector_type(4)));

__device__ __forceinline__ float bflo(unsigned u) { return __uint_as_float(u << 16); }
__device__ __forceinline__ float bfhi(unsigned u) { return __uint_as_float(u & 0xffff0000u); }
__device__ __forceinline__ unsigned short f2bf(float f) {
    unsigned u = __float_as_uint(f);
    unsigned r = (u + 0x7fffu + ((u >> 16) & 1u)) >> 16;   // round-nearest-even
    return (unsigned short)r;
}

// Convert + transpose weights once: wt[n][k] = bf16(W[k][n]).
__global__ void prep_w_kernel(const float* __restrict__ W1, const float* __restrict__ W2,
                              unsigned short* __restrict__ wt1, unsigned short* __restrict__ wt2) {
    int i = blockIdx.x * 256 + threadIdx.x;
    if (i < DH * DIN) {                       // wt1 [128][256]
        int nn = i >> 8, k = i & 255;
        wt1[i] = f2bf(W1[k * DH + nn]);
    } else {
        int j = i - DH * DIN;
        if (j < DOUT * DH) {                  // wt2 [64][128]
            int nn = j >> 7, k = j & 127;
            wt2[j] = f2bf(W2[k * DOUT + nn]);
        }
    }
}

// Pass 1: per-block bucket histogram (LDS), write bh[p][NB].
__launch_bounds__(256)
__global__ void hist_kernel(const int* __restrict__ col, int* __restrict__ bh,
                            int E, int Ec, int NB) {
    __shared__ int hist[NBMAX];
    int p = blockIdx.x, t = threadIdx.x;
    for (int b = t; b < NB; b += 256) hist[b] = 0;
    __syncthreads();
    int s = p * Ec, e = min(s + Ec, E);
    for (int i = s + t; i < e; i += 256) atomicAdd(&hist[col[i] / NPB], 1);
    __syncthreads();
    for (int b = t; b < NB; b += 256) bh[p * NB + b] = hist[b];
}

// Pass 2: per-bucket column scan over blocks (exclusive, in place).
__launch_bounds__(512)
__global__ void colscan_kernel(int* __restrict__ bh, int* __restrict__ btotal,
                               int P, int NB) {
    __shared__ int arr[512];
    int b = blockIdx.x, t = threadIdx.x;
    arr[t] = (t < P) ? bh[t * NB + b] : 0;
    __syncthreads();
    for (int off = 1; off < 512; off <<= 1) {
        int v = (t >= off) ? arr[t - off] : 0;
        __syncthreads();
        arr[t] += v;
        __syncthreads();
    }
    int excl = (t == 0) ? 0 : arr[t - 1];
    if (t < P) bh[t * NB + b] = excl;
    if (t == P - 1) btotal[b] = arr[t];
}

// Pass 2b: exclusive scan of btotal -> bbase[0..NB]; rowptr[n]=E.
__launch_bounds__(512)
__global__ void basescan_kernel(const int* __restrict__ btotal, int* __restrict__ bbase,
                                int* __restrict__ rowptr, int NB, int n, int E) {
    __shared__ int arr[512];
    int t = threadIdx.x;
    arr[t] = (t < NB) ? btotal[t] : 0;
    __syncthreads();
    for (int off = 1; off < 512; off <<= 1) {
        int v = (t >= off) ? arr[t - off] : 0;
        __syncthreads();
        arr[t] += v;
        __syncthreads();
    }
    int excl = (t == 0) ? 0 : arr[t - 1];
    if (t <= NB) bbase[t] = excl;
    if (t == 511) rowptr[n] = E;
}

// Pass 3: scatter edges into bucket-partitioned order via LDS cursors.
// part[pos] = (row | col_local<<16, w_bits).
__launch_bounds__(256)
__global__ void scatter_kernel(const int* __restrict__ row, const int* __restrict__ col,
                               const float* __restrict__ w, const int* __restrict__ bh,
                               const int* __restrict__ bbase, int2* __restrict__ part,
                               int E, int Ec, int NB) {
    __shared__ int cur[NBMAX];
    int p = blockIdx.x, t = threadIdx.x;
    for (int b = t; b < NB; b += 256) cur[b] = bbase[b] + bh[p * NB + b];
    __syncthreads();
    int s = p * Ec, e = min(s + Ec, E);
    for (int i = s + t; i < e; i += 256) {
        int c = col[i];
        int r = row[i];
        int b = c / NPB;
        int pos = atomicAdd(&cur[b], 1);          // LDS atomic
        part[pos] = make_int2(r | ((c - b * NPB) << 16), __float_as_int(w[i]));
    }
}

// Pass 4: one block per bucket: per-node deg/dinv/rowptr + per-node CSR.
// Edge record packed to 4B: src(u16) | half(w)<<16.
__launch_bounds__(256)
__global__ void bucket_csr_kernel(const int2* __restrict__ part, const int* __restrict__ bbase,
                                  float* __restrict__ dinv, int* __restrict__ rowptr,
                                  unsigned* __restrict__ final_e, int n) {
    __shared__ int   hist[NPB];
    __shared__ float wsum[NPB];
    __shared__ int   nbase[NPB];
    __shared__ int   cur[NPB];
    int b = blockIdx.x, t = threadIdx.x;
    if (t < NPB) { hist[t] = 0; wsum[t] = 0.0f; }
    __syncthreads();
    int s = bbase[b], e = bbase[b + 1];
    for (int i = s + t; i < e; i += 256) {
        int2 rec = part[i];
        int cl = rec.x >> 16;
        atomicAdd(&hist[cl], 1);
        atomicAdd(&wsum[cl], __int_as_float(rec.y));
    }
    __syncthreads();
    if (t == 0) {
        int run = 0;
        for (int k = 0; k < NPB; ++k) { nbase[k] = run; run += hist[k]; }
    }
    __syncthreads();
    if (t < NPB) {
        int node = b * NPB + t;
        if (node < n) {
            dinv[node] = rsqrtf(1.0f + wsum[t]);   // deg >= 1 (self-loop)
            rowptr[node] = s + nbase[t];
        }
        cur[t] = nbase[t];
    }
    __syncthreads();
    for (int i = s + t; i < e; i += 256) {
        int2 rec = part[i];
        int cl = rec.x >> 16;
        int q = s + atomicAdd(&cur[cl], 1);       // LDS atomic
        unsigned short ws = __half_as_ushort(__float2half_rn(__int_as_float(rec.y)));
        final_e[q] = ((unsigned)rec.x & 0xffffu) | ((unsigned)ws << 16);
    }
}

// MFMA GEMM: C[r][:] = bf16( scale[r] * (A[r][:K] @ B) ), B given transposed
// bf16 as Wt[n][k] ([M][K]). Block: 64 rows x full M, 4 waves (wave = M/4 cols).
template <int K, int M>
__launch_bounds__(256)
__global__ void gemm_mfma_kernel(const float* __restrict__ A,
                                 const unsigned short* __restrict__ Wt,
                                 const float* __restrict__ scale,
                                 unsigned short* __restrict__ C, int N) {
    constexpr int BK = 64, LD = BK + 8;       // LDS k-stride (pad: 2-way-free banks)
    constexpr int WN = M / 4;                 // cols per wave
    constexpr int NT = WN / 16;               // 16x16 n-tiles per wave
    constexpr int CLD = M + 8;
    constexpr int SM = (64 * LD + M * LD) > (64 * CLD) ? (64 * LD + M * LD) : (64 * CLD);
    __shared__ unsigned short smem[SM];
    __shared__ float sdv[64];
    unsigned short* As = smem;                // [64][LD]
    unsigned short* Bs = smem + 64 * LD;      // [M][LD]

    const int tid = threadIdx.x;
    const int row0 = blockIdx.x * 64;
    const int lane = tid & 63;
    const int quad = lane >> 4, r16 = lane & 15;
    const int n0 = (tid >> 6) * WN;

    if (tid < 64) {
        int r = row0 + tid;
        sdv[tid] = (r < N) ? scale[r] : 0.0f;
    }

    f32x4 acc[4][NT];
#pragma unroll
    for (int mt = 0; mt < 4; ++mt)
#pragma unroll
        for (int nt = 0; nt < NT; ++nt)
            acc[mt][nt] = (f32x4){0.f, 0.f, 0.f, 0.f};

    for (int k0 = 0; k0 < K; k0 += BK) {
        // stage A: 64 rows x 64 k, fp32 -> bf16 (1024 float4, 4/thread)
#pragma unroll
        for (int j = 0; j < 4; ++j) {
            int idx = tid + j * 256;
            int m = idx >> 4;
            int q = idx & 15;
            int gr = row0 + m;
            float4 v = make_float4(0.f, 0.f, 0.f, 0.f);
            if (gr < N) v = *(const float4*)&A[(size_t)gr * K + k0 + q * 4];
            ushort4 s4;
            s4.x = f2bf(v.x); s4.y = f2bf(v.y); s4.z = f2bf(v.z); s4.w = f2bf(v.w);
            *(ushort4*)&As[m * LD + q * 4] = s4;
        }
        // stage B: M rows(n) x 64 k bf16 (uint4 = 8 bf16)
#pragma unroll
        for (int j = 0; j < M * 8 / 256; ++j) {
            int idx = tid + j * 256;
            int nn = idx >> 3;
            int q = idx & 7;
            uint4 v = *(const uint4*)&Wt[(size_t)nn * K + k0 + q * 8];
            *(uint4*)&Bs[nn * LD + q * 8] = v;
        }
        __syncthreads();
#pragma unroll
        for (int ks = 0; ks < BK / 32; ++ks) {
            bf16x8 af[4], bfr[NT];
#pragma unroll
            for (int nt = 0; nt < NT; ++nt)
                bfr[nt] = *(const bf16x8*)&Bs[(n0 + nt * 16 + r16) * LD + ks * 32 + quad * 8];
#pragma unroll
            for (int mt = 0; mt < 4; ++mt)
                af[mt] = *(const bf16x8*)&As[(mt * 16 + r16) * LD + ks * 32 + quad * 8];
#pragma unroll
            for (int mt = 0; mt < 4; ++mt)
#pragma unroll
                for (int nt = 0; nt < NT; ++nt)
                    acc[mt][nt] = __builtin_amdgcn_mfma_f32_16x16x32_bf16(
                        af[mt], bfr[nt], acc[mt][nt], 0, 0, 0);
        }
        __syncthreads();
    }
    // epilogue: scale, bf16, LDS transpose-stage for coalesced stores
    unsigned short* Cs = smem;                // [64][CLD]
#pragma unroll
    for (int mt = 0; mt < 4; ++mt) {
#pragma unroll
        for (int i = 0; i < 4; ++i) {
            int r = mt * 16 + quad * 4 + i;
            float sc = sdv[r];
#pragma unroll
            for (int nt = 0; nt < NT; ++nt)
                Cs[r * CLD + n0 + nt * 16 + r16] = f2bf(acc[mt][nt][i] * sc);
        }
    }
    __syncthreads();
#pragma unroll
    for (int j = 0; j < 64 * M / 8 / 256; ++j) {
        int idx = tid + j * 256;
        int r = idx / (M / 8);
        int q = idx % (M / 8);
        int gr = row0 + r;
        if (gr < N) {
            uint4 v = *(const uint4*)&Cs[r * CLD + q * 8];
            *(uint4*)&C[(size_t)gr * M + q * 8] = v;
        }
    }
}

// Sliced aggregation pass: gathers only bytes [64*pslice, 64*pslice+64) of
// each bf16 row (slice working set 3.2MB -> L2-resident per XCD).
// 1 wave/node, 16 edge-slots x 4 lanes; lane = (slot, q): uint4 gather of
// features [32*pslice + 8q .. +8). Uniform round count (wave-uniform node).
// Writes out columns [32*pslice, +32) with bias (+ReLU if RELU).
template <int ROWSHIFT, bool RELU>
__launch_bounds__(256, 8)
__global__ void aggs_kernel(const unsigned short* __restrict__ xw,
                            const int* __restrict__ rowptr,
                            const unsigned* __restrict__ edge,   // src|half(w)<<16
                            const float* __restrict__ dinv,
                            const float* __restrict__ bias,
                            float* __restrict__ out, int n, int pslice) {
    constexpr int OUTV4 = (1 << ROWSHIFT) / 8;      // float4s per out row
    int node = blockIdx.x * 4 + (threadIdx.x >> 6);
    if (node >= n) return;
    int lane = threadIdx.x & 63;
    int slot = lane >> 2, q = lane & 3;
    const char* xb = (const char*)xw;
    const unsigned soff = (unsigned)pslice * 64 + (unsigned)q * 16;

    float a0 = 0.f, a1 = 0.f, a2 = 0.f, a3 = 0.f;
    float a4 = 0.f, a5 = 0.f, a6 = 0.f, a7 = 0.f;
    if (slot == 0) {                                 // self term, weight 1
        uint4 u = *(const uint4*)(xb + (((unsigned)node) << ROWSHIFT) + soff);
        a0 = bflo(u.x); a1 = bfhi(u.x); a2 = bflo(u.y); a3 = bfhi(u.y);
        a4 = bflo(u.z); a5 = bfhi(u.z); a6 = bflo(u.w); a7 = bfhi(u.w);
    }

    int p0 = rowptr[node], p1 = rowptr[node + 1];
    int last = p1 - 1;
    int nr = (p1 - p0 + 15) >> 4;                    // wave-uniform rounds
    int idx = p0 + slot;
    unsigned rec = edge[(idx <= last) ? idx : ((last >= 0) ? last : 0)];
#pragma unroll 1
    for (int r = 0; r < nr; ++r) {
        bool on = idx <= last;
        unsigned src = rec & 0xffffu;
        float w = on ? __half2float(__ushort_as_half((unsigned short)(rec >> 16))) : 0.0f;
        uint4 v = *(const uint4*)(xb + (src << ROWSHIFT) + soff);
        idx += 16;
        int ns = (idx <= last) ? idx : ((last >= 0) ? last : 0);
        rec = edge[ns];                              // prefetch next round
        a0 += w * bflo(v.x); a1 += w * bfhi(v.x);
        a2 += w * bflo(v.y); a3 += w * bfhi(v.y);
        a4 += w * bflo(v.z); a5 += w * bfhi(v.z);
        a6 += w * bflo(v.w); a7 += w * bfhi(v.w);
    }
    // butterfly reduce over the 16 slots (lane bits 2..5)
#define REDSL(x) x += __shfl_xor(x, 4); x += __shfl_xor(x, 8); \
                 x += __shfl_xor(x, 16); x += __shfl_xor(x, 32);
    REDSL(a0) REDSL(a1) REDSL(a2) REDSL(a3)
    REDSL(a4) REDSL(a5) REDSL(a6) REDSL(a7)
#undef REDSL
    if (slot == 0) {
        float di = dinv[node];
        const float4* bp = (const float4*)bias;
        float4 b0 = bp[pslice * 8 + q * 2], b1 = bp[pslice * 8 + q * 2 + 1];
        float4 o0 = make_float4(di * a0 + b0.x, di * a1 + b0.y,
                                di * a2 + b0.z, di * a3 + b0.w);
        float4 o1 = make_float4(di * a4 + b1.x, di * a5 + b1.y,
                                di * a6 + b1.z, di * a7 + b1.w);
        if (RELU) {
            o0.x = fmaxf(o0.x, 0.f); o0.y = fmaxf(o0.y, 0.f);
            o0.z = fmaxf(o0.z, 0.f); o0.w = fmaxf(o0.w, 0.f);
            o1.x = fmaxf(o1.x, 0.f); o1.y = fmaxf(o1.y, 0.f);
            o1.z = fmaxf(o1.z, 0.f); o1.w = fmaxf(o1.w, 0.f);
        }
        ((float4*)out)[(size_t)node * OUTV4 + pslice * 8 + q * 2]     = o0;
        ((float4*)out)[(size_t)node * OUTV4 + pslice * 8 + q * 2 + 1] = o1;
    }
}

// In-place log_softmax over 64-float rows: 16 lanes/node, 4 nodes/wave.
__launch_bounds__(256, 8)
__global__ void lsm_kernel(float* __restrict__ out, int n) {
    int node = blockIdx.x * 16 + (threadIdx.x >> 4);
    if (node >= n) return;
    int s = threadIdx.x & 15;
    float4 v = ((const float4*)out)[(size_t)node * 16 + s];
    float m = fmaxf(fmaxf(v.x, v.y), fmaxf(v.z, v.w));
    m = fmaxf(m, __shfl_xor(m, 1));
    m = fmaxf(m, __shfl_xor(m, 2));
    m = fmaxf(m, __shfl_xor(m, 4));
    m = fmaxf(m, __shfl_xor(m, 8));
    float e = __expf(v.x - m) + __expf(v.y - m) + __expf(v.z - m) + __expf(v.w - m);
    e += __shfl_xor(e, 1);
    e += __shfl_xor(e, 2);
    e += __shfl_xor(e, 4);
    e += __shfl_xor(e, 8);
    float lse = m + __logf(e);
    ((float4*)out)[(size_t)node * 16 + s] =
        make_float4(v.x - lse, v.y - lse, v.z - lse, v.w - lse);
}

extern "C" void kernel_launch(void* const* d_in, const int* in_sizes, int n_in,
                              void* d_out, int out_size, void* d_ws, size_t ws_size,
                              hipStream_t stream) {
    const float* x  = (const float*)d_in[0];
    const int*   ei = (const int*)d_in[1];
    const float* ew = (const float*)d_in[2];
    const float* W1 = (const float*)d_in[3];
    const float* b1 = (const float*)d_in[4];
    const float* W2 = (const float*)d_in[5];
    const float* b2 = (const float*)d_in[6];
    float* out = (float*)d_out;

    const int n = in_sizes[0] / DIN;      // 50000
    const int E = in_sizes[2];            // 1600000
    const int* row = ei;                  // edge_index[0] (source)
    const int* col = ei + E;              // edge_index[1] (target)

    const int NB = (n + NPB - 1) / NPB;   // 500 buckets
    const int P  = NB;
    const int Ec = (E + P - 1) / P;       // 3200 edges/block

    char* ptr = (char*)d_ws;
    auto alloc = [&](size_t bytes) -> void* {
        void* r = (void*)ptr;
        ptr += (bytes + 255) & ~(size_t)255;
        return r;
    };
    int*   bh     = (int*)  alloc((size_t)P * NB * 4);       // 1 MB
    int*   btotal = (int*)  alloc((size_t)NB * 4);
    int*   bbase  = (int*)  alloc((size_t)(NB + 1) * 4);
    int*   rowptr = (int*)  alloc((size_t)(n + 1) * 4);
    float* dinv   = (float*)alloc((size_t)n * 4);
    unsigned* edge = (unsigned*)alloc((size_t)E * 4);        // packed CSR edges
    unsigned short* xw1 = (unsigned short*)alloc((size_t)n * DH * 2);  // bf16 tables
    unsigned short* wt1 = (unsigned short*)alloc((size_t)DH * DIN * 2);
    unsigned short* wt2 = (unsigned short*)alloc((size_t)DOUT * DH * 2);
    // tail: part (12.8MB, build phase) then h1 (25.6MB, compute phase)
    char* tail = (char*)alloc((size_t)n * DH * 4);
    int2*  part = (int2*)tail;
    float* h1   = (float*)tail;
    unsigned short* xw2 = xw1;            // layer-2 table aliases layer-1 table

    const int nb_g = (n + 63) / 64;       // 782
    const int nb_a = (n + 3) / 4;         // 12500
    const int nb_s = (n + 15) / 16;       // 3125

    prep_w_kernel<<<(DH * DIN + DOUT * DH + 255) / 256, 256, 0, stream>>>(W1, W2, wt1, wt2);
    hist_kernel<<<P, 256, 0, stream>>>(col, bh, E, Ec, NB);
    colscan_kernel<<<NB, 512, 0, stream>>>(bh, btotal, P, NB);
    basescan_kernel<<<1, 512, 0, stream>>>(btotal, bbase, rowptr, NB, n, E);
    scatter_kernel<<<P, 256, 0, stream>>>(row, col, ew, bh, bbase, part, E, Ec, NB);
    bucket_csr_kernel<<<NB, 256, 0, stream>>>(part, bbase, dinv, rowptr, edge, n);

    gemm_mfma_kernel<DIN, DH><<<nb_g, 256, 0, stream>>>(x, wt1, dinv, xw1, n);
    for (int p = 0; p < 4; ++p)
        aggs_kernel<8, true><<<nb_a, 256, 0, stream>>>(xw1, rowptr, edge, dinv, b1, h1, n, p);
    gemm_mfma_kernel<DH, DOUT><<<nb_g, 256, 0, stream>>>(h1, wt2, dinv, xw2, n);
    for (int p = 0; p < 2; ++p)
        aggs_kernel<7, false><<<nb_a, 256, 0, stream>>>(xw2, rowptr, edge, dinv, b2, out, n, p);
    lsm_kernel<<<nb_s, 256, 0, stream>>>(out, n);
}

// Round 5
// 347.238 us; speedup vs baseline: 1.0302x; 1.0302x over previous
//
#include <hip/hip_runtime.h>
#include <hip/hip_bf16.h>
#include <hip/hip_fp16.h>
#include <cstddef>

// ---------------------------------------------------------------------------
// GCN 2-layer forward.
//  h1 = relu(Agg(x @ W1) + b1);  out = log_softmax(Agg(h1 @ W2) + b2)
//  Agg(z)[i] = dinv[i]^2 z[i] + sum_{e: col[e]==i} dinv[row] w dinv[i] z[row]
// Round 7: sliced aggregation, overhead-amortized.
//  * R6 post-mortem: slicing fixed the L2-miss wall but 16-slot layout left
//    only ~2 rounds/node/pass -> per-pass fixed cost (prologue + 32-shfl
//    reduce) dominated; 6 dispatches added launch gaps. 282->358 regression.
//  * Now: 16 lanes/node (4 edge-slots x 4 feature-lanes), 4 nodes/wave ->
//    ~8 rounds/pass, 16-shfl reduce, 4x better amortization.
//  * All slices of a layer in ONE dispatch (pslice = blockIdx.x / nbg);
//    block-order keeps slices temporally separated for L2 residency.
//  * Non-temporal record loads + output stores protect the resident slice.
//  * log_softmax separate tiny kernel; edge records 4B (src:u16, w:fp16).
//  * GEMMs via bf16 MFMA (16x16x32), dinv-scaling fused epilogue (unchanged).
// ---------------------------------------------------------------------------

#define DIN 256
#define DH  128
#define DOUT 64
#define NPB 100        // nodes per bucket (50000/100 = 500 buckets)
#define NBMAX 512      // max buckets (shared-array size)

typedef __bf16 bf16x8 __attribute__((ext_vector_type(8)));
typedef float f32x4 __attribute__((ext_vector_type(4)));
typedef unsigned uintx4 __attribute__((ext_vector_type(4)));

__device__ __forceinline__ float bflo(unsigned u) { return __uint_as_float(u << 16); }
__device__ __forceinline__ float bfhi(unsigned u) { return __uint_as_float(u & 0xffff0000u); }
__device__ __forceinline__ unsigned short f2bf(float f) {
    unsigned u = __float_as_uint(f);
    unsigned r = (u + 0x7fffu + ((u >> 16) & 1u)) >> 16;   // round-nearest-even
    return (unsigned short)r;
}

// Convert + transpose weights once: wt[n][k] = bf16(W[k][n]).
__global__ void prep_w_kernel(const float* __restrict__ W1, const float* __restrict__ W2,
                              unsigned short* __restrict__ wt1, unsigned short* __restrict__ wt2) {
    int i = blockIdx.x * 256 + threadIdx.x;
    if (i < DH * DIN) {                       // wt1 [128][256]
        int nn = i >> 8, k = i & 255;
        wt1[i] = f2bf(W1[k * DH + nn]);
    } else {
        int j = i - DH * DIN;
        if (j < DOUT * DH) {                  // wt2 [64][128]
            int nn = j >> 7, k = j & 127;
            wt2[j] = f2bf(W2[k * DOUT + nn]);
        }
    }
}

// Pass 1: per-block bucket histogram (LDS), write bh[p][NB].
__launch_bounds__(256)
__global__ void hist_kernel(const int* __restrict__ col, int* __restrict__ bh,
                            int E, int Ec, int NB) {
    __shared__ int hist[NBMAX];
    int p = blockIdx.x, t = threadIdx.x;
    for (int b = t; b < NB; b += 256) hist[b] = 0;
    __syncthreads();
    int s = p * Ec, e = min(s + Ec, E);
    for (int i = s + t; i < e; i += 256) atomicAdd(&hist[col[i] / NPB], 1);
    __syncthreads();
    for (int b = t; b < NB; b += 256) bh[p * NB + b] = hist[b];
}

// Pass 2: per-bucket column scan over blocks (exclusive, in place).
__launch_bounds__(512)
__global__ void colscan_kernel(int* __restrict__ bh, int* __restrict__ btotal,
                               int P, int NB) {
    __shared__ int arr[512];
    int b = blockIdx.x, t = threadIdx.x;
    arr[t] = (t < P) ? bh[t * NB + b] : 0;
    __syncthreads();
    for (int off = 1; off < 512; off <<= 1) {
        int v = (t >= off) ? arr[t - off] : 0;
        __syncthreads();
        arr[t] += v;
        __syncthreads();
    }
    int excl = (t == 0) ? 0 : arr[t - 1];
    if (t < P) bh[t * NB + b] = excl;
    if (t == P - 1) btotal[b] = arr[t];
}

// Pass 2b: exclusive scan of btotal -> bbase[0..NB]; rowptr[n]=E.
__launch_bounds__(512)
__global__ void basescan_kernel(const int* __restrict__ btotal, int* __restrict__ bbase,
                                int* __restrict__ rowptr, int NB, int n, int E) {
    __shared__ int arr[512];
    int t = threadIdx.x;
    arr[t] = (t < NB) ? btotal[t] : 0;
    __syncthreads();
    for (int off = 1; off < 512; off <<= 1) {
        int v = (t >= off) ? arr[t - off] : 0;
        __syncthreads();
        arr[t] += v;
        __syncthreads();
    }
    int excl = (t == 0) ? 0 : arr[t - 1];
    if (t <= NB) bbase[t] = excl;
    if (t == 511) rowptr[n] = E;
}

// Pass 3: scatter edges into bucket-partitioned order via LDS cursors.
// part[pos] = (row | col_local<<16, w_bits).
__launch_bounds__(256)
__global__ void scatter_kernel(const int* __restrict__ row, const int* __restrict__ col,
                               const float* __restrict__ w, const int* __restrict__ bh,
                               const int* __restrict__ bbase, int2* __restrict__ part,
                               int E, int Ec, int NB) {
    __shared__ int cur[NBMAX];
    int p = blockIdx.x, t = threadIdx.x;
    for (int b = t; b < NB; b += 256) cur[b] = bbase[b] + bh[p * NB + b];
    __syncthreads();
    int s = p * Ec, e = min(s + Ec, E);
    for (int i = s + t; i < e; i += 256) {
        int c = col[i];
        int r = row[i];
        int b = c / NPB;
        int pos = atomicAdd(&cur[b], 1);          // LDS atomic
        part[pos] = make_int2(r | ((c - b * NPB) << 16), __float_as_int(w[i]));
    }
}

// Pass 4: one block per bucket: per-node deg/dinv/rowptr + per-node CSR.
// Edge record packed to 4B: src(u16) | half(w)<<16.
__launch_bounds__(256)
__global__ void bucket_csr_kernel(const int2* __restrict__ part, const int* __restrict__ bbase,
                                  float* __restrict__ dinv, int* __restrict__ rowptr,
                                  unsigned* __restrict__ final_e, int n) {
    __shared__ int   hist[NPB];
    __shared__ float wsum[NPB];
    __shared__ int   nbase[NPB];
    __shared__ int   cur[NPB];
    int b = blockIdx.x, t = threadIdx.x;
    if (t < NPB) { hist[t] = 0; wsum[t] = 0.0f; }
    __syncthreads();
    int s = bbase[b], e = bbase[b + 1];
    for (int i = s + t; i < e; i += 256) {
        int2 rec = part[i];
        int cl = rec.x >> 16;
        atomicAdd(&hist[cl], 1);
        atomicAdd(&wsum[cl], __int_as_float(rec.y));
    }
    __syncthreads();
    if (t == 0) {
        int run = 0;
        for (int k = 0; k < NPB; ++k) { nbase[k] = run; run += hist[k]; }
    }
    __syncthreads();
    if (t < NPB) {
        int node = b * NPB + t;
        if (node < n) {
            dinv[node] = rsqrtf(1.0f + wsum[t]);   // deg >= 1 (self-loop)
            rowptr[node] = s + nbase[t];
        }
        cur[t] = nbase[t];
    }
    __syncthreads();
    for (int i = s + t; i < e; i += 256) {
        int2 rec = part[i];
        int cl = rec.x >> 16;
        int q = s + atomicAdd(&cur[cl], 1);       // LDS atomic
        unsigned short ws = __half_as_ushort(__float2half_rn(__int_as_float(rec.y)));
        final_e[q] = ((unsigned)rec.x & 0xffffu) | ((unsigned)ws << 16);
    }
}

// MFMA GEMM: C[r][:] = bf16( scale[r] * (A[r][:K] @ B) ), B given transposed
// bf16 as Wt[n][k] ([M][K]). Block: 64 rows x full M, 4 waves (wave = M/4 cols).
template <int K, int M>
__launch_bounds__(256)
__global__ void gemm_mfma_kernel(const float* __restrict__ A,
                                 const unsigned short* __restrict__ Wt,
                                 const float* __restrict__ scale,
                                 unsigned short* __restrict__ C, int N) {
    constexpr int BK = 64, LD = BK + 8;       // LDS k-stride (pad: 2-way-free banks)
    constexpr int WN = M / 4;                 // cols per wave
    constexpr int NT = WN / 16;               // 16x16 n-tiles per wave
    constexpr int CLD = M + 8;
    constexpr int SM = (64 * LD + M * LD) > (64 * CLD) ? (64 * LD + M * LD) : (64 * CLD);
    __shared__ unsigned short smem[SM];
    __shared__ float sdv[64];
    unsigned short* As = smem;                // [64][LD]
    unsigned short* Bs = smem + 64 * LD;      // [M][LD]

    const int tid = threadIdx.x;
    const int row0 = blockIdx.x * 64;
    const int lane = tid & 63;
    const int quad = lane >> 4, r16 = lane & 15;
    const int n0 = (tid >> 6) * WN;

    if (tid < 64) {
        int r = row0 + tid;
        sdv[tid] = (r < N) ? scale[r] : 0.0f;
    }

    f32x4 acc[4][NT];
#pragma unroll
    for (int mt = 0; mt < 4; ++mt)
#pragma unroll
        for (int nt = 0; nt < NT; ++nt)
            acc[mt][nt] = (f32x4){0.f, 0.f, 0.f, 0.f};

    for (int k0 = 0; k0 < K; k0 += BK) {
        // stage A: 64 rows x 64 k, fp32 -> bf16 (1024 float4, 4/thread)
#pragma unroll
        for (int j = 0; j < 4; ++j) {
            int idx = tid + j * 256;
            int m = idx >> 4;
            int q = idx & 15;
            int gr = row0 + m;
            float4 v = make_float4(0.f, 0.f, 0.f, 0.f);
            if (gr < N) v = *(const float4*)&A[(size_t)gr * K + k0 + q * 4];
            ushort4 s4;
            s4.x = f2bf(v.x); s4.y = f2bf(v.y); s4.z = f2bf(v.z); s4.w = f2bf(v.w);
            *(ushort4*)&As[m * LD + q * 4] = s4;
        }
        // stage B: M rows(n) x 64 k bf16 (uint4 = 8 bf16)
#pragma unroll
        for (int j = 0; j < M * 8 / 256; ++j) {
            int idx = tid + j * 256;
            int nn = idx >> 3;
            int q = idx & 7;
            uint4 v = *(const uint4*)&Wt[(size_t)nn * K + k0 + q * 8];
            *(uint4*)&Bs[nn * LD + q * 8] = v;
        }
        __syncthreads();
#pragma unroll
        for (int ks = 0; ks < BK / 32; ++ks) {
            bf16x8 af[4], bfr[NT];
#pragma unroll
            for (int nt = 0; nt < NT; ++nt)
                bfr[nt] = *(const bf16x8*)&Bs[(n0 + nt * 16 + r16) * LD + ks * 32 + quad * 8];
#pragma unroll
            for (int mt = 0; mt < 4; ++mt)
                af[mt] = *(const bf16x8*)&As[(mt * 16 + r16) * LD + ks * 32 + quad * 8];
#pragma unroll
            for (int mt = 0; mt < 4; ++mt)
#pragma unroll
                for (int nt = 0; nt < NT; ++nt)
                    acc[mt][nt] = __builtin_amdgcn_mfma_f32_16x16x32_bf16(
                        af[mt], bfr[nt], acc[mt][nt], 0, 0, 0);
        }
        __syncthreads();
    }
    // epilogue: scale, bf16, LDS transpose-stage for coalesced stores
    unsigned short* Cs = smem;                // [64][CLD]
#pragma unroll
    for (int mt = 0; mt < 4; ++mt) {
#pragma unroll
        for (int i = 0; i < 4; ++i) {
            int r = mt * 16 + quad * 4 + i;
            float sc = sdv[r];
#pragma unroll
            for (int nt = 0; nt < NT; ++nt)
                Cs[r * CLD + n0 + nt * 16 + r16] = f2bf(acc[mt][nt][i] * sc);
        }
    }
    __syncthreads();
#pragma unroll
    for (int j = 0; j < 64 * M / 8 / 256; ++j) {
        int idx = tid + j * 256;
        int r = idx / (M / 8);
        int q = idx % (M / 8);
        int gr = row0 + r;
        if (gr < N) {
            uint4 v = *(const uint4*)&Cs[r * CLD + q * 8];
            *(uint4*)&C[(size_t)gr * M + q * 8] = v;
        }
    }
}

// Sliced aggregation, all slices in one dispatch (pslice = blockIdx.x / nbg;
// block order keeps one slice hot in L2 at a time; slice = 3.2MB < 4MB L2).
// 16 lanes/node (slot=0..3 edge-slots x q=0..3 feature-lanes), 4 nodes/wave,
// 16 nodes/block. Round = 4 edges/node; ~8 rounds at avg degree 32.
// Gathers one 64B line/edge; records/outputs use non-temporal ops so the
// streaming traffic does not evict the resident slice.
template <int ROWSHIFT, bool RELU>
__launch_bounds__(256, 8)
__global__ void aggs_kernel(const unsigned short* __restrict__ xw,
                            const int* __restrict__ rowptr,
                            const unsigned* __restrict__ edge,   // src|half(w)<<16
                            const float* __restrict__ dinv,
                            const float* __restrict__ bias,
                            float* __restrict__ out, int n, int nbg) {
    constexpr int OUTV4 = (1 << ROWSHIFT) / 8;      // float4s per out row
    int pslice = blockIdx.x / nbg;
    int gb = blockIdx.x % nbg;
    int node = gb * 16 + (threadIdx.x >> 4);
    if (node >= n) return;
    int l16 = threadIdx.x & 15;
    int slot = l16 >> 2, q = l16 & 3;
    const char* xb = (const char*)xw;
    const unsigned soff = (unsigned)pslice * 64 + (unsigned)q * 16;

    float a0 = 0.f, a1 = 0.f, a2 = 0.f, a3 = 0.f;
    float a4 = 0.f, a5 = 0.f, a6 = 0.f, a7 = 0.f;
    if (slot == 0) {                                 // self term, weight 1
        uint4 u = *(const uint4*)(xb + (((unsigned)node) << ROWSHIFT) + soff);
        a0 = bflo(u.x); a1 = bfhi(u.x); a2 = bflo(u.y); a3 = bfhi(u.y);
        a4 = bflo(u.z); a5 = bfhi(u.z); a6 = bflo(u.w); a7 = bfhi(u.w);
    }

    int p0 = rowptr[node], p1 = rowptr[node + 1];
    int last = p1 - 1;
    int nr = (p1 - p0 + 3) >> 2;                     // group-uniform rounds
    int idx = p0 + slot;
    int ns = (idx <= last) ? idx : ((last >= 0) ? last : 0);
    unsigned rec = __builtin_nontemporal_load(&edge[ns]);
#pragma unroll 1
    for (int r = 0; r < nr; ++r) {
        bool on = idx <= last;
        unsigned src = rec & 0xffffu;
        float w = on ? __half2float(__ushort_as_half((unsigned short)(rec >> 16))) : 0.0f;
        uint4 v = *(const uint4*)(xb + (src << ROWSHIFT) + soff);
        idx += 4;
        ns = (idx <= last) ? idx : ((last >= 0) ? last : 0);
        rec = __builtin_nontemporal_load(&edge[ns]);   // prefetch next round
        a0 += w * bflo(v.x); a1 += w * bfhi(v.x);
        a2 += w * bflo(v.y); a3 += w * bfhi(v.y);
        a4 += w * bflo(v.z); a5 += w * bfhi(v.z);
        a6 += w * bflo(v.w); a7 += w * bfhi(v.w);
    }
    // reduce over the 4 slots (lane bits 2,3)
#define REDSL(x) x += __shfl_xor(x, 4); x += __shfl_xor(x, 8);
    REDSL(a0) REDSL(a1) REDSL(a2) REDSL(a3)
    REDSL(a4) REDSL(a5) REDSL(a6) REDSL(a7)
#undef REDSL
    if (slot == 0) {
        float di = dinv[node];
        const float4* bp = (const float4*)bias;
        float4 b0 = bp[pslice * 8 + q * 2], b1 = bp[pslice * 8 + q * 2 + 1];
        f32x4 o0 = {di * a0 + b0.x, di * a1 + b0.y, di * a2 + b0.z, di * a3 + b0.w};
        f32x4 o1 = {di * a4 + b1.x, di * a5 + b1.y, di * a6 + b1.z, di * a7 + b1.w};
        if (RELU) {
            o0.x = fmaxf(o0.x, 0.f); o0.y = fmaxf(o0.y, 0.f);
            o0.z = fmaxf(o0.z, 0.f); o0.w = fmaxf(o0.w, 0.f);
            o1.x = fmaxf(o1.x, 0.f); o1.y = fmaxf(o1.y, 0.f);
            o1.z = fmaxf(o1.z, 0.f); o1.w = fmaxf(o1.w, 0.f);
        }
        f32x4* op = (f32x4*)out + (size_t)node * OUTV4 + pslice * 8 + q * 2;
        __builtin_nontemporal_store(o0, op);
        __builtin_nontemporal_store(o1, op + 1);
    }
}

// In-place log_softmax over 64-float rows: 16 lanes/node, 4 nodes/wave.
__launch_bounds__(256, 8)
__global__ void lsm_kernel(float* __restrict__ out, int n) {
    int node = blockIdx.x * 16 + (threadIdx.x >> 4);
    if (node >= n) return;
    int s = threadIdx.x & 15;
    float4 v = ((const float4*)out)[(size_t)node * 16 + s];
    float m = fmaxf(fmaxf(v.x, v.y), fmaxf(v.z, v.w));
    m = fmaxf(m, __shfl_xor(m, 1));
    m = fmaxf(m, __shfl_xor(m, 2));
    m = fmaxf(m, __shfl_xor(m, 4));
    m = fmaxf(m, __shfl_xor(m, 8));
    float e = __expf(v.x - m) + __expf(v.y - m) + __expf(v.z - m) + __expf(v.w - m);
    e += __shfl_xor(e, 1);
    e += __shfl_xor(e, 2);
    e += __shfl_xor(e, 4);
    e += __shfl_xor(e, 8);
    float lse = m + __logf(e);
    ((float4*)out)[(size_t)node * 16 + s] =
        make_float4(v.x - lse, v.y - lse, v.z - lse, v.w - lse);
}

extern "C" void kernel_launch(void* const* d_in, const int* in_sizes, int n_in,
                              void* d_out, int out_size, void* d_ws, size_t ws_size,
                              hipStream_t stream) {
    const float* x  = (const float*)d_in[0];
    const int*   ei = (const int*)d_in[1];
    const float* ew = (const float*)d_in[2];
    const float* W1 = (const float*)d_in[3];
    const float* b1 = (const float*)d_in[4];
    const float* W2 = (const float*)d_in[5];
    const float* b2 = (const float*)d_in[6];
    float* out = (float*)d_out;

    const int n = in_sizes[0] / DIN;      // 50000
    const int E = in_sizes[2];            // 1600000
    const int* row = ei;                  // edge_index[0] (source)
    const int* col = ei + E;              // edge_index[1] (target)

    const int NB = (n + NPB - 1) / NPB;   // 500 buckets
    const int P  = NB;
    const int Ec = (E + P - 1) / P;       // 3200 edges/block

    char* ptr = (char*)d_ws;
    auto alloc = [&](size_t bytes) -> void* {
        void* r = (void*)ptr;
        ptr += (bytes + 255) & ~(size_t)255;
        return r;
    };
    int*   bh     = (int*)  alloc((size_t)P * NB * 4);       // 1 MB
    int*   btotal = (int*)  alloc((size_t)NB * 4);
    int*   bbase  = (int*)  alloc((size_t)(NB + 1) * 4);
    int*   rowptr = (int*)  alloc((size_t)(n + 1) * 4);
    float* dinv   = (float*)alloc((size_t)n * 4);
    unsigned* edge = (unsigned*)alloc((size_t)E * 4);        // packed CSR edges
    unsigned short* xw1 = (unsigned short*)alloc((size_t)n * DH * 2);  // bf16 tables
    unsigned short* wt1 = (unsigned short*)alloc((size_t)DH * DIN * 2);
    unsigned short* wt2 = (unsigned short*)alloc((size_t)DOUT * DH * 2);
    // tail: part (12.8MB, build phase) then h1 (25.6MB, compute phase)
    char* tail = (char*)alloc((size_t)n * DH * 4);
    int2*  part = (int2*)tail;
    float* h1   = (float*)tail;
    unsigned short* xw2 = xw1;            // layer-2 table aliases layer-1 table

    const int nb_g = (n + 63) / 64;       // 782
    const int nbg  = (n + 15) / 16;       // 3125 (16 nodes/block)
    const int nb_s = (n + 15) / 16;       // 3125

    prep_w_kernel<<<(DH * DIN + DOUT * DH + 255) / 256, 256, 0, stream>>>(W1, W2, wt1, wt2);
    hist_kernel<<<P, 256, 0, stream>>>(col, bh, E, Ec, NB);
    colscan_kernel<<<NB, 512, 0, stream>>>(bh, btotal, P, NB);
    basescan_kernel<<<1, 512, 0, stream>>>(btotal, bbase, rowptr, NB, n, E);
    scatter_kernel<<<P, 256, 0, stream>>>(row, col, ew, bh, bbase, part, E, Ec, NB);
    bucket_csr_kernel<<<NB, 256, 0, stream>>>(part, bbase, dinv, rowptr, edge, n);

    gemm_mfma_kernel<DIN, DH><<<nb_g, 256, 0, stream>>>(x, wt1, dinv, xw1, n);
    aggs_kernel<8, true><<<nbg * 4, 256, 0, stream>>>(xw1, rowptr, edge, dinv, b1, h1, n, nbg);
    gemm_mfma_kernel<DH, DOUT><<<nb_g, 256, 0, stream>>>(h1, wt2, dinv, xw2, n);
    aggs_kernel<7, false><<<nbg * 2, 256, 0, stream>>>(xw2, rowptr, edge, dinv, b2, out, n, nbg);
    lsm_kernel<<<nb_s, 256, 0, stream>>>(out, n);
}

// Round 6
// 322.639 us; speedup vs baseline: 1.1087x; 1.0762x over previous
//
#include <hip/hip_runtime.h>
#include <hip/hip_bf16.h>
#include <hip/hip_fp16.h>
#include <cstddef>

// ---------------------------------------------------------------------------
// GCN 2-layer forward.
//  h1 = relu(Agg(x @ W1) + b1);  out = log_softmax(Agg(h1 @ W2) + b2)
//  Agg(z)[i] = dinv[i]^2 z[i] + sum_{e: col[e]==i} dinv[row] w dinv[i] z[row]
// Round 8: SLICE-MAJOR gather table.
//  * R7 post-mortem: strided 64B slices wasted half of every >=128B fetch
//    (FETCH 266MB ~= 2x ideal). Now the GEMM epilogue stores the bf16 table
//    as xw_s[slice][node][32 feats] -> pass p gathers from one contiguous
//    3.2MB block (fits 4MB/XCD L2), 128B fetches fully same-slice.
//  * aggs: 16 lanes/node (4 edge-slots x 4 feature-lanes), all slices in one
//    dispatch (block order separates slices), NT record loads + NT output
//    stores protect residency. Edge records 4B (src:u16, w:fp16).
//  * log_softmax separate tiny kernel.
//  * GEMMs via bf16 MFMA (16x16x32), dinv-scaling fused epilogue.
// ---------------------------------------------------------------------------

#define DIN 256
#define DH  128
#define DOUT 64
#define NPB 100        // nodes per bucket (50000/100 = 500 buckets)
#define NBMAX 512      // max buckets (shared-array size)

typedef __bf16 bf16x8 __attribute__((ext_vector_type(8)));
typedef float f32x4 __attribute__((ext_vector_type(4)));

__device__ __forceinline__ float bflo(unsigned u) { return __uint_as_float(u << 16); }
__device__ __forceinline__ float bfhi(unsigned u) { return __uint_as_float(u & 0xffff0000u); }
__device__ __forceinline__ unsigned short f2bf(float f) {
    unsigned u = __float_as_uint(f);
    unsigned r = (u + 0x7fffu + ((u >> 16) & 1u)) >> 16;   // round-nearest-even
    return (unsigned short)r;
}

// Convert + transpose weights once: wt[n][k] = bf16(W[k][n]).
__global__ void prep_w_kernel(const float* __restrict__ W1, const float* __restrict__ W2,
                              unsigned short* __restrict__ wt1, unsigned short* __restrict__ wt2) {
    int i = blockIdx.x * 256 + threadIdx.x;
    if (i < DH * DIN) {                       // wt1 [128][256]
        int nn = i >> 8, k = i & 255;
        wt1[i] = f2bf(W1[k * DH + nn]);
    } else {
        int j = i - DH * DIN;
        if (j < DOUT * DH) {                  // wt2 [64][128]
            int nn = j >> 7, k = j & 127;
            wt2[j] = f2bf(W2[k * DOUT + nn]);
        }
    }
}

// Pass 1: per-block bucket histogram (LDS), write bh[p][NB].
__launch_bounds__(256)
__global__ void hist_kernel(const int* __restrict__ col, int* __restrict__ bh,
                            int E, int Ec, int NB) {
    __shared__ int hist[NBMAX];
    int p = blockIdx.x, t = threadIdx.x;
    for (int b = t; b < NB; b += 256) hist[b] = 0;
    __syncthreads();
    int s = p * Ec, e = min(s + Ec, E);
    for (int i = s + t; i < e; i += 256) atomicAdd(&hist[col[i] / NPB], 1);
    __syncthreads();
    for (int b = t; b < NB; b += 256) bh[p * NB + b] = hist[b];
}

// Pass 2: per-bucket column scan over blocks (exclusive, in place).
__launch_bounds__(512)
__global__ void colscan_kernel(int* __restrict__ bh, int* __restrict__ btotal,
                               int P, int NB) {
    __shared__ int arr[512];
    int b = blockIdx.x, t = threadIdx.x;
    arr[t] = (t < P) ? bh[t * NB + b] : 0;
    __syncthreads();
    for (int off = 1; off < 512; off <<= 1) {
        int v = (t >= off) ? arr[t - off] : 0;
        __syncthreads();
        arr[t] += v;
        __syncthreads();
    }
    int excl = (t == 0) ? 0 : arr[t - 1];
    if (t < P) bh[t * NB + b] = excl;
    if (t == P - 1) btotal[b] = arr[t];
}

// Pass 2b: exclusive scan of btotal -> bbase[0..NB]; rowptr[n]=E.
__launch_bounds__(512)
__global__ void basescan_kernel(const int* __restrict__ btotal, int* __restrict__ bbase,
                                int* __restrict__ rowptr, int NB, int n, int E) {
    __shared__ int arr[512];
    int t = threadIdx.x;
    arr[t] = (t < NB) ? btotal[t] : 0;
    __syncthreads();
    for (int off = 1; off < 512; off <<= 1) {
        int v = (t >= off) ? arr[t - off] : 0;
        __syncthreads();
        arr[t] += v;
        __syncthreads();
    }
    int excl = (t == 0) ? 0 : arr[t - 1];
    if (t <= NB) bbase[t] = excl;
    if (t == 511) rowptr[n] = E;
}

// Pass 3: scatter edges into bucket-partitioned order via LDS cursors.
// part[pos] = (row | col_local<<16, w_bits).
__launch_bounds__(256)
__global__ void scatter_kernel(const int* __restrict__ row, const int* __restrict__ col,
                               const float* __restrict__ w, const int* __restrict__ bh,
                               const int* __restrict__ bbase, int2* __restrict__ part,
                               int E, int Ec, int NB) {
    __shared__ int cur[NBMAX];
    int p = blockIdx.x, t = threadIdx.x;
    for (int b = t; b < NB; b += 256) cur[b] = bbase[b] + bh[p * NB + b];
    __syncthreads();
    int s = p * Ec, e = min(s + Ec, E);
    for (int i = s + t; i < e; i += 256) {
        int c = col[i];
        int r = row[i];
        int b = c / NPB;
        int pos = atomicAdd(&cur[b], 1);          // LDS atomic
        part[pos] = make_int2(r | ((c - b * NPB) << 16), __float_as_int(w[i]));
    }
}

// Pass 4: one block per bucket: per-node deg/dinv/rowptr + per-node CSR.
// Edge record packed to 4B: src(u16) | half(w)<<16.
__launch_bounds__(256)
__global__ void bucket_csr_kernel(const int2* __restrict__ part, const int* __restrict__ bbase,
                                  float* __restrict__ dinv, int* __restrict__ rowptr,
                                  unsigned* __restrict__ final_e, int n) {
    __shared__ int   hist[NPB];
    __shared__ float wsum[NPB];
    __shared__ int   nbase[NPB];
    __shared__ int   cur[NPB];
    int b = blockIdx.x, t = threadIdx.x;
    if (t < NPB) { hist[t] = 0; wsum[t] = 0.0f; }
    __syncthreads();
    int s = bbase[b], e = bbase[b + 1];
    for (int i = s + t; i < e; i += 256) {
        int2 rec = part[i];
        int cl = rec.x >> 16;
        atomicAdd(&hist[cl], 1);
        atomicAdd(&wsum[cl], __int_as_float(rec.y));
    }
    __syncthreads();
    if (t == 0) {
        int run = 0;
        for (int k = 0; k < NPB; ++k) { nbase[k] = run; run += hist[k]; }
    }
    __syncthreads();
    if (t < NPB) {
        int node = b * NPB + t;
        if (node < n) {
            dinv[node] = rsqrtf(1.0f + wsum[t]);   // deg >= 1 (self-loop)
            rowptr[node] = s + nbase[t];
        }
        cur[t] = nbase[t];
    }
    __syncthreads();
    for (int i = s + t; i < e; i += 256) {
        int2 rec = part[i];
        int cl = rec.x >> 16;
        int q = s + atomicAdd(&cur[cl], 1);       // LDS atomic
        unsigned short ws = __half_as_ushort(__float2half_rn(__int_as_float(rec.y)));
        final_e[q] = ((unsigned)rec.x & 0xffffu) | ((unsigned)ws << 16);
    }
}

// MFMA GEMM with SLICE-MAJOR output: C_s[slice][r][32] = bf16(scale[r]*(A@B))
// slice = output-column/32. B given transposed bf16 as Wt[n][k] ([M][K]).
// Block: 64 rows x full M, 4 waves (wave = M/4 cols).
template <int K, int M>
__launch_bounds__(256)
__global__ void gemm_mfma_kernel(const float* __restrict__ A,
                                 const unsigned short* __restrict__ Wt,
                                 const float* __restrict__ scale,
                                 unsigned short* __restrict__ C, int N) {
    constexpr int BK = 64, LD = BK + 8;       // LDS k-stride (pad: 2-way-free banks)
    constexpr int WN = M / 4;                 // cols per wave
    constexpr int NT = WN / 16;               // 16x16 n-tiles per wave
    constexpr int CLD = M + 8;
    constexpr int SM = (64 * LD + M * LD) > (64 * CLD) ? (64 * LD + M * LD) : (64 * CLD);
    __shared__ unsigned short smem[SM];
    __shared__ float sdv[64];
    unsigned short* As = smem;                // [64][LD]
    unsigned short* Bs = smem + 64 * LD;      // [M][LD]

    const int tid = threadIdx.x;
    const int row0 = blockIdx.x * 64;
    const int lane = tid & 63;
    const int quad = lane >> 4, r16 = lane & 15;
    const int n0 = (tid >> 6) * WN;

    if (tid < 64) {
        int r = row0 + tid;
        sdv[tid] = (r < N) ? scale[r] : 0.0f;
    }

    f32x4 acc[4][NT];
#pragma unroll
    for (int mt = 0; mt < 4; ++mt)
#pragma unroll
        for (int nt = 0; nt < NT; ++nt)
            acc[mt][nt] = (f32x4){0.f, 0.f, 0.f, 0.f};

    for (int k0 = 0; k0 < K; k0 += BK) {
        // stage A: 64 rows x 64 k, fp32 -> bf16 (1024 float4, 4/thread)
#pragma unroll
        for (int j = 0; j < 4; ++j) {
            int idx = tid + j * 256;
            int m = idx >> 4;
            int q = idx & 15;
            int gr = row0 + m;
            float4 v = make_float4(0.f, 0.f, 0.f, 0.f);
            if (gr < N) v = *(const float4*)&A[(size_t)gr * K + k0 + q * 4];
            ushort4 s4;
            s4.x = f2bf(v.x); s4.y = f2bf(v.y); s4.z = f2bf(v.z); s4.w = f2bf(v.w);
            *(ushort4*)&As[m * LD + q * 4] = s4;
        }
        // stage B: M rows(n) x 64 k bf16 (uint4 = 8 bf16)
#pragma unroll
        for (int j = 0; j < M * 8 / 256; ++j) {
            int idx = tid + j * 256;
            int nn = idx >> 3;
            int q = idx & 7;
            uint4 v = *(const uint4*)&Wt[(size_t)nn * K + k0 + q * 8];
            *(uint4*)&Bs[nn * LD + q * 8] = v;
        }
        __syncthreads();
#pragma unroll
        for (int ks = 0; ks < BK / 32; ++ks) {
            bf16x8 af[4], bfr[NT];
#pragma unroll
            for (int nt = 0; nt < NT; ++nt)
                bfr[nt] = *(const bf16x8*)&Bs[(n0 + nt * 16 + r16) * LD + ks * 32 + quad * 8];
#pragma unroll
            for (int mt = 0; mt < 4; ++mt)
                af[mt] = *(const bf16x8*)&As[(mt * 16 + r16) * LD + ks * 32 + quad * 8];
#pragma unroll
            for (int mt = 0; mt < 4; ++mt)
#pragma unroll
                for (int nt = 0; nt < NT; ++nt)
                    acc[mt][nt] = __builtin_amdgcn_mfma_f32_16x16x32_bf16(
                        af[mt], bfr[nt], acc[mt][nt], 0, 0, 0);
        }
        __syncthreads();
    }
    // epilogue: scale, bf16, LDS transpose-stage, slice-major stores
    unsigned short* Cs = smem;                // [64][CLD]
#pragma unroll
    for (int mt = 0; mt < 4; ++mt) {
#pragma unroll
        for (int i = 0; i < 4; ++i) {
            int r = mt * 16 + quad * 4 + i;
            float sc = sdv[r];
#pragma unroll
            for (int nt = 0; nt < NT; ++nt)
                Cs[r * CLD + n0 + nt * 16 + r16] = f2bf(acc[mt][nt][i] * sc);
        }
    }
    __syncthreads();
#pragma unroll
    for (int j = 0; j < 64 * M / 8 / 256; ++j) {
        int idx = tid + j * 256;
        int r = idx / (M / 8);
        int q = idx % (M / 8);
        int gr = row0 + r;
        if (gr < N) {
            uint4 v = *(const uint4*)&Cs[r * CLD + q * 8];
            // slice-major: C_s[q>>2][gr][ (q&3)*8 .. +8 )
            *(uint4*)&C[((size_t)(q >> 2) * N + gr) * 32 + (q & 3) * 8] = v;
        }
    }
}

// Sliced aggregation over slice-major table: pass p gathers from the
// contiguous 3.2MB block xw + p*n*32 (fits 4MB/XCD L2; 128B fetches fully
// same-slice). 16 lanes/node (4 edge-slots x 4 feature-lanes), 16 nodes/
// block, all slices in one dispatch (pslice = blockIdx.x / nbg).
// NT record loads / output stores protect the resident slice.
template <int OUTV4, bool RELU>     // OUTV4 = float4s per output row
__launch_bounds__(256, 8)
__global__ void aggs_kernel(const unsigned short* __restrict__ xw,   // [NS][n][32] bf16
                            const int* __restrict__ rowptr,
                            const unsigned* __restrict__ edge,       // src|half(w)<<16
                            const float* __restrict__ dinv,
                            const float* __restrict__ bias,
                            float* __restrict__ out, int n, int nbg) {
    int pslice = blockIdx.x / nbg;
    int gb = blockIdx.x % nbg;
    int node = gb * 16 + (threadIdx.x >> 4);
    if (node >= n) return;
    int l16 = threadIdx.x & 15;
    int slot = l16 >> 2, q = l16 & 3;
    const char* xb = (const char*)xw + (size_t)pslice * n * 64;   // slice base
    const unsigned qoff = (unsigned)q * 16;

    float a0 = 0.f, a1 = 0.f, a2 = 0.f, a3 = 0.f;
    float a4 = 0.f, a5 = 0.f, a6 = 0.f, a7 = 0.f;
    if (slot == 0) {                                 // self term, weight 1
        uint4 u = *(const uint4*)(xb + (unsigned)node * 64 + qoff);
        a0 = bflo(u.x); a1 = bfhi(u.x); a2 = bflo(u.y); a3 = bfhi(u.y);
        a4 = bflo(u.z); a5 = bfhi(u.z); a6 = bflo(u.w); a7 = bfhi(u.w);
    }

    int p0 = rowptr[node], p1 = rowptr[node + 1];
    int last = p1 - 1;
    int nr = (p1 - p0 + 3) >> 2;                     // group-uniform rounds
    int idx = p0 + slot;
    int ns = (idx <= last) ? idx : ((last >= 0) ? last : 0);
    unsigned rec = __builtin_nontemporal_load(&edge[ns]);
#pragma unroll 1
    for (int r = 0; r < nr; ++r) {
        bool on = idx <= last;
        unsigned src = rec & 0xffffu;
        float w = on ? __half2float(__ushort_as_half((unsigned short)(rec >> 16))) : 0.0f;
        uint4 v = *(const uint4*)(xb + src * 64 + qoff);
        idx += 4;
        ns = (idx <= last) ? idx : ((last >= 0) ? last : 0);
        rec = __builtin_nontemporal_load(&edge[ns]);   // prefetch next round
        a0 += w * bflo(v.x); a1 += w * bfhi(v.x);
        a2 += w * bflo(v.y); a3 += w * bfhi(v.y);
        a4 += w * bflo(v.z); a5 += w * bfhi(v.z);
        a6 += w * bflo(v.w); a7 += w * bfhi(v.w);
    }
    // reduce over the 4 slots (lane bits 2,3)
#define REDSL(x) x += __shfl_xor(x, 4); x += __shfl_xor(x, 8);
    REDSL(a0) REDSL(a1) REDSL(a2) REDSL(a3)
    REDSL(a4) REDSL(a5) REDSL(a6) REDSL(a7)
#undef REDSL
    if (slot == 0) {
        float di = dinv[node];
        const float4* bp = (const float4*)bias;
        float4 b0 = bp[pslice * 8 + q * 2], b1 = bp[pslice * 8 + q * 2 + 1];
        f32x4 o0 = {di * a0 + b0.x, di * a1 + b0.y, di * a2 + b0.z, di * a3 + b0.w};
        f32x4 o1 = {di * a4 + b1.x, di * a5 + b1.y, di * a6 + b1.z, di * a7 + b1.w};
        if (RELU) {
            o0.x = fmaxf(o0.x, 0.f); o0.y = fmaxf(o0.y, 0.f);
            o0.z = fmaxf(o0.z, 0.f); o0.w = fmaxf(o0.w, 0.f);
            o1.x = fmaxf(o1.x, 0.f); o1.y = fmaxf(o1.y, 0.f);
            o1.z = fmaxf(o1.z, 0.f); o1.w = fmaxf(o1.w, 0.f);
        }
        f32x4* op = (f32x4*)out + (size_t)node * OUTV4 + pslice * 8 + q * 2;
        __builtin_nontemporal_store(o0, op);
        __builtin_nontemporal_store(o1, op + 1);
    }
}

// In-place log_softmax over 64-float rows: 16 lanes/node, 4 nodes/wave.
__launch_bounds__(256, 8)
__global__ void lsm_kernel(float* __restrict__ out, int n) {
    int node = blockIdx.x * 16 + (threadIdx.x >> 4);
    if (node >= n) return;
    int s = threadIdx.x & 15;
    float4 v = ((const float4*)out)[(size_t)node * 16 + s];
    float m = fmaxf(fmaxf(v.x, v.y), fmaxf(v.z, v.w));
    m = fmaxf(m, __shfl_xor(m, 1));
    m = fmaxf(m, __shfl_xor(m, 2));
    m = fmaxf(m, __shfl_xor(m, 4));
    m = fmaxf(m, __shfl_xor(m, 8));
    float e = __expf(v.x - m) + __expf(v.y - m) + __expf(v.z - m) + __expf(v.w - m);
    e += __shfl_xor(e, 1);
    e += __shfl_xor(e, 2);
    e += __shfl_xor(e, 4);
    e += __shfl_xor(e, 8);
    float lse = m + __logf(e);
    ((float4*)out)[(size_t)node * 16 + s] =
        make_float4(v.x - lse, v.y - lse, v.z - lse, v.w - lse);
}

extern "C" void kernel_launch(void* const* d_in, const int* in_sizes, int n_in,
                              void* d_out, int out_size, void* d_ws, size_t ws_size,
                              hipStream_t stream) {
    const float* x  = (const float*)d_in[0];
    const int*   ei = (const int*)d_in[1];
    const float* ew = (const float*)d_in[2];
    const float* W1 = (const float*)d_in[3];
    const float* b1 = (const float*)d_in[4];
    const float* W2 = (const float*)d_in[5];
    const float* b2 = (const float*)d_in[6];
    float* out = (float*)d_out;

    const int n = in_sizes[0] / DIN;      // 50000
    const int E = in_sizes[2];            // 1600000
    const int* row = ei;                  // edge_index[0] (source)
    const int* col = ei + E;              // edge_index[1] (target)

    const int NB = (n + NPB - 1) / NPB;   // 500 buckets
    const int P  = NB;
    const int Ec = (E + P - 1) / P;       // 3200 edges/block

    char* ptr = (char*)d_ws;
    auto alloc = [&](size_t bytes) -> void* {
        void* r = (void*)ptr;
        ptr += (bytes + 255) & ~(size_t)255;
        return r;
    };
    int*   bh     = (int*)  alloc((size_t)P * NB * 4);       // 1 MB
    int*   btotal = (int*)  alloc((size_t)NB * 4);
    int*   bbase  = (int*)  alloc((size_t)(NB + 1) * 4);
    int*   rowptr = (int*)  alloc((size_t)(n + 1) * 4);
    float* dinv   = (float*)alloc((size_t)n * 4);
    unsigned* edge = (unsigned*)alloc((size_t)E * 4);        // packed CSR edges
    unsigned short* xw1 = (unsigned short*)alloc((size_t)n * DH * 2);  // bf16 tables
    unsigned short* wt1 = (unsigned short*)alloc((size_t)DH * DIN * 2);
    unsigned short* wt2 = (unsigned short*)alloc((size_t)DOUT * DH * 2);
    // tail: part (12.8MB, build phase) then h1 (25.6MB, compute phase)
    char* tail = (char*)alloc((size_t)n * DH * 4);
    int2*  part = (int2*)tail;
    float* h1   = (float*)tail;
    unsigned short* xw2 = xw1;            // layer-2 table aliases layer-1 table

    const int nb_g = (n + 63) / 64;       // 782
    const int nbg  = (n + 15) / 16;       // 3125 (16 nodes/block)
    const int nb_s = (n + 15) / 16;       // 3125

    prep_w_kernel<<<(DH * DIN + DOUT * DH + 255) / 256, 256, 0, stream>>>(W1, W2, wt1, wt2);
    hist_kernel<<<P, 256, 0, stream>>>(col, bh, E, Ec, NB);
    colscan_kernel<<<NB, 512, 0, stream>>>(bh, btotal, P, NB);
    basescan_kernel<<<1, 512, 0, stream>>>(btotal, bbase, rowptr, NB, n, E);
    scatter_kernel<<<P, 256, 0, stream>>>(row, col, ew, bh, bbase, part, E, Ec, NB);
    bucket_csr_kernel<<<NB, 256, 0, stream>>>(part, bbase, dinv, rowptr, edge, n);

    gemm_mfma_kernel<DIN, DH><<<nb_g, 256, 0, stream>>>(x, wt1, dinv, xw1, n);
    aggs_kernel<32, true><<<nbg * 4, 256, 0, stream>>>(xw1, rowptr, edge, dinv, b1, h1, n, nbg);
    gemm_mfma_kernel<DH, DOUT><<<nb_g, 256, 0, stream>>>(h1, wt2, dinv, xw2, n);
    aggs_kernel<16, false><<<nbg * 2, 256, 0, stream>>>(xw2, rowptr, edge, dinv, b2, out, n, nbg);
    lsm_kernel<<<nb_s, 256, 0, stream>>>(out, n);
}

// Round 7
// 276.076 us; speedup vs baseline: 1.2957x; 1.1687x over previous
//
#include <hip/hip_runtime.h>
#include <hip/hip_bf16.h>
#include <hip/hip_fp16.h>
#include <cstddef>

// ---------------------------------------------------------------------------
// GCN 2-layer forward.
//  h1 = relu(Agg(x @ W1) + b1);  out = log_softmax(Agg(h1 @ W2) + b2)
//  Agg(z)[i] = dinv[i]^2 z[i] + sum_{e: col[e]==i} dinv[row] w dinv[i] z[row]
// Round 9: revert to full-row gathers (R3 structure = best measured), plus:
//  * R7/R8 post-mortem: slicing cut FETCH 266->133MB but 4x edge-visits made
//    per-visit overhead dominate (86us @ 1.9TB/s, nothing saturated). Full-row
//    = fewest visits; R3 ran 57us @ 4TB/s.
//  * 4B edge records (src:u16 | fp16 w)  [from R6, halves record stream]
//  * 2-deep gather pipeline: next round's records+gathers issue before this
//    round's FMA block -> ~8KB in flight per wave (was 4KB).
//  * branch-free clamped tail round (no serial remainder).
//  * agg2 keeps fused log_softmax; GEMM epilogue row-major bf16 tables,
//    dinv pre-scaled; MFMA 16x16x32.
// ---------------------------------------------------------------------------

#define DIN 256
#define DH  128
#define DOUT 64
#define NPB 100        // nodes per bucket (50000/100 = 500 buckets)
#define NBMAX 512      // max buckets (shared-array size)

typedef __bf16 bf16x8 __attribute__((ext_vector_type(8)));
typedef float f32x4 __attribute__((ext_vector_type(4)));

__device__ __forceinline__ float bflo(unsigned u) { return __uint_as_float(u << 16); }
__device__ __forceinline__ float bfhi(unsigned u) { return __uint_as_float(u & 0xffff0000u); }
__device__ __forceinline__ unsigned short f2bf(float f) {
    unsigned u = __float_as_uint(f);
    unsigned r = (u + 0x7fffu + ((u >> 16) & 1u)) >> 16;   // round-nearest-even
    return (unsigned short)r;
}
__device__ __forceinline__ float wdec(unsigned rec) {      // fp16 weight in hi16
    return __half2float(__ushort_as_half((unsigned short)(rec >> 16)));
}

// Convert + transpose weights once: wt[n][k] = bf16(W[k][n]).
__global__ void prep_w_kernel(const float* __restrict__ W1, const float* __restrict__ W2,
                              unsigned short* __restrict__ wt1, unsigned short* __restrict__ wt2) {
    int i = blockIdx.x * 256 + threadIdx.x;
    if (i < DH * DIN) {                       // wt1 [128][256]
        int nn = i >> 8, k = i & 255;
        wt1[i] = f2bf(W1[k * DH + nn]);
    } else {
        int j = i - DH * DIN;
        if (j < DOUT * DH) {                  // wt2 [64][128]
            int nn = j >> 7, k = j & 127;
            wt2[j] = f2bf(W2[k * DOUT + nn]);
        }
    }
}

// Pass 1: per-block bucket histogram (LDS), write bh[p][NB].
__launch_bounds__(256)
__global__ void hist_kernel(const int* __restrict__ col, int* __restrict__ bh,
                            int E, int Ec, int NB) {
    __shared__ int hist[NBMAX];
    int p = blockIdx.x, t = threadIdx.x;
    for (int b = t; b < NB; b += 256) hist[b] = 0;
    __syncthreads();
    int s = p * Ec, e = min(s + Ec, E);
    for (int i = s + t; i < e; i += 256) atomicAdd(&hist[col[i] / NPB], 1);
    __syncthreads();
    for (int b = t; b < NB; b += 256) bh[p * NB + b] = hist[b];
}

// Pass 2: per-bucket column scan over blocks (exclusive, in place).
__launch_bounds__(512)
__global__ void colscan_kernel(int* __restrict__ bh, int* __restrict__ btotal,
                               int P, int NB) {
    __shared__ int arr[512];
    int b = blockIdx.x, t = threadIdx.x;
    arr[t] = (t < P) ? bh[t * NB + b] : 0;
    __syncthreads();
    for (int off = 1; off < 512; off <<= 1) {
        int v = (t >= off) ? arr[t - off] : 0;
        __syncthreads();
        arr[t] += v;
        __syncthreads();
    }
    int excl = (t == 0) ? 0 : arr[t - 1];
    if (t < P) bh[t * NB + b] = excl;
    if (t == P - 1) btotal[b] = arr[t];
}

// Pass 2b: exclusive scan of btotal -> bbase[0..NB]; rowptr[n]=E.
__launch_bounds__(512)
__global__ void basescan_kernel(const int* __restrict__ btotal, int* __restrict__ bbase,
                                int* __restrict__ rowptr, int NB, int n, int E) {
    __shared__ int arr[512];
    int t = threadIdx.x;
    arr[t] = (t < NB) ? btotal[t] : 0;
    __syncthreads();
    for (int off = 1; off < 512; off <<= 1) {
        int v = (t >= off) ? arr[t - off] : 0;
        __syncthreads();
        arr[t] += v;
        __syncthreads();
    }
    int excl = (t == 0) ? 0 : arr[t - 1];
    if (t <= NB) bbase[t] = excl;
    if (t == 511) rowptr[n] = E;
}

// Pass 3: scatter edges into bucket-partitioned order via LDS cursors.
// part[pos] = (row | col_local<<16, w_bits).
__launch_bounds__(256)
__global__ void scatter_kernel(const int* __restrict__ row, const int* __restrict__ col,
                               const float* __restrict__ w, const int* __restrict__ bh,
                               const int* __restrict__ bbase, int2* __restrict__ part,
                               int E, int Ec, int NB) {
    __shared__ int cur[NBMAX];
    int p = blockIdx.x, t = threadIdx.x;
    for (int b = t; b < NB; b += 256) cur[b] = bbase[b] + bh[p * NB + b];
    __syncthreads();
    int s = p * Ec, e = min(s + Ec, E);
    for (int i = s + t; i < e; i += 256) {
        int c = col[i];
        int r = row[i];
        int b = c / NPB;
        int pos = atomicAdd(&cur[b], 1);          // LDS atomic
        part[pos] = make_int2(r | ((c - b * NPB) << 16), __float_as_int(w[i]));
    }
}

// Pass 4: one block per bucket: per-node deg/dinv/rowptr + per-node CSR.
// Edge record packed to 4B: src(u16) | half(w)<<16.
__launch_bounds__(256)
__global__ void bucket_csr_kernel(const int2* __restrict__ part, const int* __restrict__ bbase,
                                  float* __restrict__ dinv, int* __restrict__ rowptr,
                                  unsigned* __restrict__ final_e, int n) {
    __shared__ int   hist[NPB];
    __shared__ float wsum[NPB];
    __shared__ int   nbase[NPB];
    __shared__ int   cur[NPB];
    int b = blockIdx.x, t = threadIdx.x;
    if (t < NPB) { hist[t] = 0; wsum[t] = 0.0f; }
    __syncthreads();
    int s = bbase[b], e = bbase[b + 1];
    for (int i = s + t; i < e; i += 256) {
        int2 rec = part[i];
        int cl = rec.x >> 16;
        atomicAdd(&hist[cl], 1);
        atomicAdd(&wsum[cl], __int_as_float(rec.y));
    }
    __syncthreads();
    if (t == 0) {
        int run = 0;
        for (int k = 0; k < NPB; ++k) { nbase[k] = run; run += hist[k]; }
    }
    __syncthreads();
    if (t < NPB) {
        int node = b * NPB + t;
        if (node < n) {
            dinv[node] = rsqrtf(1.0f + wsum[t]);   // deg >= 1 (self-loop)
            rowptr[node] = s + nbase[t];
        }
        cur[t] = nbase[t];
    }
    __syncthreads();
    for (int i = s + t; i < e; i += 256) {
        int2 rec = part[i];
        int cl = rec.x >> 16;
        int q = s + atomicAdd(&cur[cl], 1);       // LDS atomic
        unsigned short ws = __half_as_ushort(__float2half_rn(__int_as_float(rec.y)));
        final_e[q] = ((unsigned)rec.x & 0xffffu) | ((unsigned)ws << 16);
    }
}

// MFMA GEMM: C[r][:] = bf16( scale[r] * (A[r][:K] @ B) ), B given transposed
// bf16 as Wt[n][k] ([M][K]). Block: 64 rows x full M, 4 waves (wave = M/4 cols).
template <int K, int M>
__launch_bounds__(256)
__global__ void gemm_mfma_kernel(const float* __restrict__ A,
                                 const unsigned short* __restrict__ Wt,
                                 const float* __restrict__ scale,
                                 unsigned short* __restrict__ C, int N) {
    constexpr int BK = 64, LD = BK + 8;       // LDS k-stride (pad: 2-way-free banks)
    constexpr int WN = M / 4;                 // cols per wave
    constexpr int NT = WN / 16;               // 16x16 n-tiles per wave
    constexpr int CLD = M + 8;
    constexpr int SM = (64 * LD + M * LD) > (64 * CLD) ? (64 * LD + M * LD) : (64 * CLD);
    __shared__ unsigned short smem[SM];
    __shared__ float sdv[64];
    unsigned short* As = smem;                // [64][LD]
    unsigned short* Bs = smem + 64 * LD;      // [M][LD]

    const int tid = threadIdx.x;
    const int row0 = blockIdx.x * 64;
    const int lane = tid & 63;
    const int quad = lane >> 4, r16 = lane & 15;
    const int n0 = (tid >> 6) * WN;

    if (tid < 64) {
        int r = row0 + tid;
        sdv[tid] = (r < N) ? scale[r] : 0.0f;
    }

    f32x4 acc[4][NT];
#pragma unroll
    for (int mt = 0; mt < 4; ++mt)
#pragma unroll
        for (int nt = 0; nt < NT; ++nt)
            acc[mt][nt] = (f32x4){0.f, 0.f, 0.f, 0.f};

    for (int k0 = 0; k0 < K; k0 += BK) {
        // stage A: 64 rows x 64 k, fp32 -> bf16 (1024 float4, 4/thread)
#pragma unroll
        for (int j = 0; j < 4; ++j) {
            int idx = tid + j * 256;
            int m = idx >> 4;
            int q = idx & 15;
            int gr = row0 + m;
            float4 v = make_float4(0.f, 0.f, 0.f, 0.f);
            if (gr < N) v = *(const float4*)&A[(size_t)gr * K + k0 + q * 4];
            ushort4 s4;
            s4.x = f2bf(v.x); s4.y = f2bf(v.y); s4.z = f2bf(v.z); s4.w = f2bf(v.w);
            *(ushort4*)&As[m * LD + q * 4] = s4;
        }
        // stage B: M rows(n) x 64 k bf16 (uint4 = 8 bf16)
#pragma unroll
        for (int j = 0; j < M * 8 / 256; ++j) {
            int idx = tid + j * 256;
            int nn = idx >> 3;
            int q = idx & 7;
            uint4 v = *(const uint4*)&Wt[(size_t)nn * K + k0 + q * 8];
            *(uint4*)&Bs[nn * LD + q * 8] = v;
        }
        __syncthreads();
#pragma unroll
        for (int ks = 0; ks < BK / 32; ++ks) {
            bf16x8 af[4], bfr[NT];
#pragma unroll
            for (int nt = 0; nt < NT; ++nt)
                bfr[nt] = *(const bf16x8*)&Bs[(n0 + nt * 16 + r16) * LD + ks * 32 + quad * 8];
#pragma unroll
            for (int mt = 0; mt < 4; ++mt)
                af[mt] = *(const bf16x8*)&As[(mt * 16 + r16) * LD + ks * 32 + quad * 8];
#pragma unroll
            for (int mt = 0; mt < 4; ++mt)
#pragma unroll
                for (int nt = 0; nt < NT; ++nt)
                    acc[mt][nt] = __builtin_amdgcn_mfma_f32_16x16x32_bf16(
                        af[mt], bfr[nt], acc[mt][nt], 0, 0, 0);
        }
        __syncthreads();
    }
    // epilogue: scale, bf16, LDS transpose-stage for coalesced stores
    unsigned short* Cs = smem;                // [64][CLD]
#pragma unroll
    for (int mt = 0; mt < 4; ++mt) {
#pragma unroll
        for (int i = 0; i < 4; ++i) {
            int r = mt * 16 + quad * 4 + i;
            float sc = sdv[r];
#pragma unroll
            for (int nt = 0; nt < NT; ++nt)
                Cs[r * CLD + n0 + nt * 16 + r16] = f2bf(acc[mt][nt][i] * sc);
        }
    }
    __syncthreads();
#pragma unroll
    for (int j = 0; j < 64 * M / 8 / 256; ++j) {
        int idx = tid + j * 256;
        int r = idx / (M / 8);
        int q = idx % (M / 8);
        int gr = row0 + r;
        if (gr < N) {
            uint4 v = *(const uint4*)&Cs[r * CLD + q * 8];
            *(uint4*)&C[(size_t)gr * M + q * 8] = v;
        }
    }
}

#define ACC8(v, wgt)                                            \
    a0 += (wgt) * bflo((v).x); a1 += (wgt) * bfhi((v).x);       \
    a2 += (wgt) * bflo((v).y); a3 += (wgt) * bfhi((v).y);       \
    a4 += (wgt) * bflo((v).z); a5 += (wgt) * bfhi((v).z);       \
    a6 += (wgt) * bflo((v).w); a7 += (wgt) * bfhi((v).w);

// Layer-1 aggregation: 1 wave/node, 4 slots x 16 lanes, uint4 full-row
// gathers (256B/row, 16 edges/round). 2-deep pipeline: round r+1's records
// AND gathers issue before round r's FMA block (~8KB in flight/wave).
__launch_bounds__(256, 6)
__global__ void agg1_kernel(const unsigned short* __restrict__ xw,   // bf16 [n][128] (pre-scaled)
                            const int* __restrict__ rowptr,
                            const unsigned* __restrict__ edge,       // src|half(w)<<16
                            const float* __restrict__ dinv,
                            const float* __restrict__ bias,          // fp32 [128]
                            float* __restrict__ out, int n) {        // fp32 [n][128]
    int node = blockIdx.x * 4 + (threadIdx.x >> 6);
    if (node >= n) return;
    int lane = threadIdx.x & 63;
    int qw = lane >> 4, sub = lane & 15;
    const char* xb = (const char*)xw;
    const unsigned ssub = (unsigned)sub << 4;       // byte offset in 256B row
    float di = dinv[node];

    float a0 = 0.f, a1 = 0.f, a2 = 0.f, a3 = 0.f;
    float a4 = 0.f, a5 = 0.f, a6 = 0.f, a7 = 0.f;
    if (qw == 0) {                                   // self term, weight 1
        uint4 u = *(const uint4*)(xb + (((unsigned)node) << 8) + ssub);
        a0 = bflo(u.x); a1 = bfhi(u.x); a2 = bflo(u.y); a3 = bfhi(u.y);
        a4 = bflo(u.z); a5 = bfhi(u.z); a6 = bflo(u.w); a7 = bfhi(u.w);
    }

    int p = rowptr[node], p1 = rowptr[node + 1];
    int sb = 4 * qw;
    unsigned r0, r1, r2, r3;
    uint4 v0, v1, v2, v3;
    bool have = (p + 16 <= p1);
    if (have) {
        const unsigned* rp = edge + p + sb;
        r0 = __builtin_nontemporal_load(rp);
        r1 = __builtin_nontemporal_load(rp + 1);
        r2 = __builtin_nontemporal_load(rp + 2);
        r3 = __builtin_nontemporal_load(rp + 3);
        v0 = *(const uint4*)(xb + ((r0 & 0xffffu) << 8) + ssub);
        v1 = *(const uint4*)(xb + ((r1 & 0xffffu) << 8) + ssub);
        v2 = *(const uint4*)(xb + ((r2 & 0xffffu) << 8) + ssub);
        v3 = *(const uint4*)(xb + ((r3 & 0xffffu) << 8) + ssub);
    }
#pragma unroll 1
    while (have) {
        p += 16;
        bool havn = (p + 16 <= p1);
        unsigned m0 = 0, m1 = 0, m2 = 0, m3 = 0;
        uint4 u0 = {0,0,0,0}, u1 = {0,0,0,0}, u2 = {0,0,0,0}, u3 = {0,0,0,0};
        if (havn) {                                  // next records + gathers
            const unsigned* rp = edge + p + sb;
            m0 = __builtin_nontemporal_load(rp);
            m1 = __builtin_nontemporal_load(rp + 1);
            m2 = __builtin_nontemporal_load(rp + 2);
            m3 = __builtin_nontemporal_load(rp + 3);
            u0 = *(const uint4*)(xb + ((m0 & 0xffffu) << 8) + ssub);
            u1 = *(const uint4*)(xb + ((m1 & 0xffffu) << 8) + ssub);
            u2 = *(const uint4*)(xb + ((m2 & 0xffffu) << 8) + ssub);
            u3 = *(const uint4*)(xb + ((m3 & 0xffffu) << 8) + ssub);
        }
        float w0 = wdec(r0), w1 = wdec(r1), w2 = wdec(r2), w3 = wdec(r3);
        ACC8(v0, w0); ACC8(v1, w1); ACC8(v2, w2); ACC8(v3, w3);
        r0 = m0; r1 = m1; r2 = m2; r3 = m3;
        v0 = u0; v1 = u1; v2 = u2; v3 = u3;
        have = havn;
    }
    int rem = p1 - p;                                // 0..15, one clamped round
    if (rem > 0) {
        int last = p1 - 1, b = p + sb;
        unsigned e0 = edge[min(b, last)],     e1 = edge[min(b + 1, last)];
        unsigned e2 = edge[min(b + 2, last)], e3 = edge[min(b + 3, last)];
        float w0 = (b     <= last) ? wdec(e0) : 0.f;
        float w1 = (b + 1 <= last) ? wdec(e1) : 0.f;
        float w2 = (b + 2 <= last) ? wdec(e2) : 0.f;
        float w3 = (b + 3 <= last) ? wdec(e3) : 0.f;
        uint4 t0 = *(const uint4*)(xb + ((e0 & 0xffffu) << 8) + ssub);
        uint4 t1 = *(const uint4*)(xb + ((e1 & 0xffffu) << 8) + ssub);
        uint4 t2 = *(const uint4*)(xb + ((e2 & 0xffffu) << 8) + ssub);
        uint4 t3 = *(const uint4*)(xb + ((e3 & 0xffffu) << 8) + ssub);
        ACC8(t0, w0); ACC8(t1, w1); ACC8(t2, w2); ACC8(t3, w3);
    }
    // reduce over the 4 slots (lane bits 4,5)
    a0 += __shfl_xor(a0, 16); a0 += __shfl_xor(a0, 32);
    a1 += __shfl_xor(a1, 16); a1 += __shfl_xor(a1, 32);
    a2 += __shfl_xor(a2, 16); a2 += __shfl_xor(a2, 32);
    a3 += __shfl_xor(a3, 16); a3 += __shfl_xor(a3, 32);
    a4 += __shfl_xor(a4, 16); a4 += __shfl_xor(a4, 32);
    a5 += __shfl_xor(a5, 16); a5 += __shfl_xor(a5, 32);
    a6 += __shfl_xor(a6, 16); a6 += __shfl_xor(a6, 32);
    a7 += __shfl_xor(a7, 16); a7 += __shfl_xor(a7, 32);
    if (qw < 2) {
        float4 b = ((const float4*)bias)[2 * sub + qw];
        f32x4 o;
        if (qw == 0) { o.x = a0; o.y = a1; o.z = a2; o.w = a3; }
        else         { o.x = a4; o.y = a5; o.z = a6; o.w = a7; }
        o.x = fmaxf(di * o.x + b.x, 0.f);
        o.y = fmaxf(di * o.y + b.y, 0.f);
        o.z = fmaxf(di * o.z + b.z, 0.f);
        o.w = fmaxf(di * o.w + b.w, 0.f);
        __builtin_nontemporal_store(o, (f32x4*)out + (size_t)node * 32 + 2 * sub + qw);
    }
}

// Layer-2 aggregation + log_softmax: 1 wave/node, 8 slots x 8 lanes, uint4
// full-row gathers (128B/row, 32 edges/round), same 2-deep pipeline.
__launch_bounds__(256, 6)
__global__ void agg2_kernel(const unsigned short* __restrict__ xw,   // bf16 [n][64] (pre-scaled)
                            const int* __restrict__ rowptr,
                            const unsigned* __restrict__ edge,
                            const float* __restrict__ dinv,
                            const float* __restrict__ bias,          // fp32 [64]
                            float* __restrict__ out, int n) {        // fp32 [n][64]
    int node = blockIdx.x * 4 + (threadIdx.x >> 6);
    if (node >= n) return;
    int lane = threadIdx.x & 63;
    int oct = lane >> 3, sub = lane & 7;
    const char* xb = (const char*)xw;
    const unsigned ssub = (unsigned)sub << 4;       // byte offset in 128B row
    float di = dinv[node];

    float a0 = 0.f, a1 = 0.f, a2 = 0.f, a3 = 0.f;
    float a4 = 0.f, a5 = 0.f, a6 = 0.f, a7 = 0.f;
    if (oct == 0) {                                  // self term, weight 1
        uint4 u = *(const uint4*)(xb + (((unsigned)node) << 7) + ssub);
        a0 = bflo(u.x); a1 = bfhi(u.x); a2 = bflo(u.y); a3 = bfhi(u.y);
        a4 = bflo(u.z); a5 = bfhi(u.z); a6 = bflo(u.w); a7 = bfhi(u.w);
    }

    int p = rowptr[node], p1 = rowptr[node + 1];
    int sb = 4 * oct;
    unsigned r0, r1, r2, r3;
    uint4 v0, v1, v2, v3;
    bool have = (p + 32 <= p1);
    if (have) {
        const unsigned* rp = edge + p + sb;
        r0 = __builtin_nontemporal_load(rp);
        r1 = __builtin_nontemporal_load(rp + 1);
        r2 = __builtin_nontemporal_load(rp + 2);
        r3 = __builtin_nontemporal_load(rp + 3);
        v0 = *(const uint4*)(xb + ((r0 & 0xffffu) << 7) + ssub);
        v1 = *(const uint4*)(xb + ((r1 & 0xffffu) << 7) + ssub);
        v2 = *(const uint4*)(xb + ((r2 & 0xffffu) << 7) + ssub);
        v3 = *(const uint4*)(xb + ((r3 & 0xffffu) << 7) + ssub);
    }
#pragma unroll 1
    while (have) {
        p += 32;
        bool havn = (p + 32 <= p1);
        unsigned m0 = 0, m1 = 0, m2 = 0, m3 = 0;
        uint4 u0 = {0,0,0,0}, u1 = {0,0,0,0}, u2 = {0,0,0,0}, u3 = {0,0,0,0};
        if (havn) {
            const unsigned* rp = edge + p + sb;
            m0 = __builtin_nontemporal_load(rp);
            m1 = __builtin_nontemporal_load(rp + 1);
            m2 = __builtin_nontemporal_load(rp + 2);
            m3 = __builtin_nontemporal_load(rp + 3);
            u0 = *(const uint4*)(xb + ((m0 & 0xffffu) << 7) + ssub);
            u1 = *(const uint4*)(xb + ((m1 & 0xffffu) << 7) + ssub);
            u2 = *(const uint4*)(xb + ((m2 & 0xffffu) << 7) + ssub);
            u3 = *(const uint4*)(xb + ((m3 & 0xffffu) << 7) + ssub);
        }
        float w0 = wdec(r0), w1 = wdec(r1), w2 = wdec(r2), w3 = wdec(r3);
        ACC8(v0, w0); ACC8(v1, w1); ACC8(v2, w2); ACC8(v3, w3);
        r0 = m0; r1 = m1; r2 = m2; r3 = m3;
        v0 = u0; v1 = u1; v2 = u2; v3 = u3;
        have = havn;
    }
    int rem = p1 - p;                                // 0..31, one clamped round
    if (rem > 0) {
        int last = p1 - 1, b = p + sb;
        unsigned e0 = edge[min(b, last)],     e1 = edge[min(b + 1, last)];
        unsigned e2 = edge[min(b + 2, last)], e3 = edge[min(b + 3, last)];
        float w0 = (b     <= last) ? wdec(e0) : 0.f;
        float w1 = (b + 1 <= last) ? wdec(e1) : 0.f;
        float w2 = (b + 2 <= last) ? wdec(e2) : 0.f;
        float w3 = (b + 3 <= last) ? wdec(e3) : 0.f;
        uint4 t0 = *(const uint4*)(xb + ((e0 & 0xffffu) << 7) + ssub);
        uint4 t1 = *(const uint4*)(xb + ((e1 & 0xffffu) << 7) + ssub);
        uint4 t2 = *(const uint4*)(xb + ((e2 & 0xffffu) << 7) + ssub);
        uint4 t3 = *(const uint4*)(xb + ((e3 & 0xffffu) << 7) + ssub);
        ACC8(t0, w0); ACC8(t1, w1); ACC8(t2, w2); ACC8(t3, w3);
    }
    // reduce over the 8 slots (lane bits 3,4,5)
    a0 += __shfl_xor(a0, 8); a0 += __shfl_xor(a0, 16); a0 += __shfl_xor(a0, 32);
    a1 += __shfl_xor(a1, 8); a1 += __shfl_xor(a1, 16); a1 += __shfl_xor(a1, 32);
    a2 += __shfl_xor(a2, 8); a2 += __shfl_xor(a2, 16); a2 += __shfl_xor(a2, 32);
    a3 += __shfl_xor(a3, 8); a3 += __shfl_xor(a3, 16); a3 += __shfl_xor(a3, 32);
    a4 += __shfl_xor(a4, 8); a4 += __shfl_xor(a4, 16); a4 += __shfl_xor(a4, 32);
    a5 += __shfl_xor(a5, 8); a5 += __shfl_xor(a5, 16); a5 += __shfl_xor(a5, 32);
    a6 += __shfl_xor(a6, 8); a6 += __shfl_xor(a6, 16); a6 += __shfl_xor(a6, 32);
    a7 += __shfl_xor(a7, 8); a7 += __shfl_xor(a7, 16); a7 += __shfl_xor(a7, 32);
    // bias + dinv, then log_softmax over the 64 features (8 per lane x sub 0..7)
    const float4* bp = (const float4*)bias;
    float4 bl = bp[2 * sub], bh = bp[2 * sub + 1];
    a0 = di * a0 + bl.x; a1 = di * a1 + bl.y; a2 = di * a2 + bl.z; a3 = di * a3 + bl.w;
    a4 = di * a4 + bh.x; a5 = di * a5 + bh.y; a6 = di * a6 + bh.z; a7 = di * a7 + bh.w;
    float m = fmaxf(fmaxf(fmaxf(a0, a1), fmaxf(a2, a3)),
                    fmaxf(fmaxf(a4, a5), fmaxf(a6, a7)));
    m = fmaxf(m, __shfl_xor(m, 4));
    m = fmaxf(m, __shfl_xor(m, 2));
    m = fmaxf(m, __shfl_xor(m, 1));
    float s = __expf(a0 - m) + __expf(a1 - m) + __expf(a2 - m) + __expf(a3 - m)
            + __expf(a4 - m) + __expf(a5 - m) + __expf(a6 - m) + __expf(a7 - m);
    s += __shfl_xor(s, 4);
    s += __shfl_xor(s, 2);
    s += __shfl_xor(s, 1);
    float lse = m + __logf(s);
    if (oct < 2) {
        f32x4 o;
        if (oct == 0) { o.x = a0 - lse; o.y = a1 - lse; o.z = a2 - lse; o.w = a3 - lse; }
        else          { o.x = a4 - lse; o.y = a5 - lse; o.z = a6 - lse; o.w = a7 - lse; }
        __builtin_nontemporal_store(o, (f32x4*)out + (size_t)node * 16 + 2 * sub + oct);
    }
}

extern "C" void kernel_launch(void* const* d_in, const int* in_sizes, int n_in,
                              void* d_out, int out_size, void* d_ws, size_t ws_size,
                              hipStream_t stream) {
    const float* x  = (const float*)d_in[0];
    const int*   ei = (const int*)d_in[1];
    const float* ew = (const float*)d_in[2];
    const float* W1 = (const float*)d_in[3];
    const float* b1 = (const float*)d_in[4];
    const float* W2 = (const float*)d_in[5];
    const float* b2 = (const float*)d_in[6];
    float* out = (float*)d_out;

    const int n = in_sizes[0] / DIN;      // 50000
    const int E = in_sizes[2];            // 1600000
    const int* row = ei;                  // edge_index[0] (source)
    const int* col = ei + E;              // edge_index[1] (target)

    const int NB = (n + NPB - 1) / NPB;   // 500 buckets
    const int P  = NB;
    const int Ec = (E + P - 1) / P;       // 3200 edges/block

    char* ptr = (char*)d_ws;
    auto alloc = [&](size_t bytes) -> void* {
        void* r = (void*)ptr;
        ptr += (bytes + 255) & ~(size_t)255;
        return r;
    };
    int*   bh     = (int*)  alloc((size_t)P * NB * 4);       // 1 MB
    int*   btotal = (int*)  alloc((size_t)NB * 4);
    int*   bbase  = (int*)  alloc((size_t)(NB + 1) * 4);
    int*   rowptr = (int*)  alloc((size_t)(n + 1) * 4);
    float* dinv   = (float*)alloc((size_t)n * 4);
    unsigned* edge = (unsigned*)alloc((size_t)E * 4);        // packed CSR edges
    unsigned short* xw1 = (unsigned short*)alloc((size_t)n * DH * 2);  // bf16 tables
    unsigned short* wt1 = (unsigned short*)alloc((size_t)DH * DIN * 2);
    unsigned short* wt2 = (unsigned short*)alloc((size_t)DOUT * DH * 2);
    // tail: part (12.8MB, build phase) then h1 (25.6MB, compute phase)
    char* tail = (char*)alloc((size_t)n * DH * 4);
    int2*  part = (int2*)tail;
    float* h1   = (float*)tail;
    unsigned short* xw2 = xw1;            // layer-2 table aliases layer-1 table

    const int nb_g = (n + 63) / 64;       // 782
    const int nb_a = (n + 3) / 4;         // 12500

    prep_w_kernel<<<(DH * DIN + DOUT * DH + 255) / 256, 256, 0, stream>>>(W1, W2, wt1, wt2);
    hist_kernel<<<P, 256, 0, stream>>>(col, bh, E, Ec, NB);
    colscan_kernel<<<NB, 512, 0, stream>>>(bh, btotal, P, NB);
    basescan_kernel<<<1, 512, 0, stream>>>(btotal, bbase, rowptr, NB, n, E);
    scatter_kernel<<<P, 256, 0, stream>>>(row, col, ew, bh, bbase, part, E, Ec, NB);
    bucket_csr_kernel<<<NB, 256, 0, stream>>>(part, bbase, dinv, rowptr, edge, n);

    gemm_mfma_kernel<DIN, DH><<<nb_g, 256, 0, stream>>>(x, wt1, dinv, xw1, n);
    agg1_kernel<<<nb_a, 256, 0, stream>>>(xw1, rowptr, edge, dinv, b1, h1, n);
    gemm_mfma_kernel<DH, DOUT><<<nb_g, 256, 0, stream>>>(h1, wt2, dinv, xw2, n);
    agg2_kernel<<<nb_a, 256, 0, stream>>>(xw2, rowptr, edge, dinv, b2, out, n);
}